// Round 11
// baseline (4038.686 us; speedup 1.0000x reference)
//
#include <hip/hip_runtime.h>
#include <hip/hip_bf16.h>
#include <stdint.h>

typedef unsigned short u16;
typedef __bf16 bf16t;
typedef _Float16 f16t;
typedef __attribute__((ext_vector_type(8))) bf16t bf16x8;
typedef __attribute__((ext_vector_type(4))) float f32x4;
typedef __attribute__((ext_vector_type(2))) _Float16 h2;

#define B_   512
#define N_   100
#define P_   20
#define E_   256
#define H_   512
#define G4H_ 2048
#define BT_  (B_ * N_)   // 51200
#define BC_  128         // phase-B batch chunk
#define NCHUNK_ (B_ / BC_)

__device__ __forceinline__ float bfu2f(unsigned u) {
    union { unsigned i; float f; } v; v.i = u << 16; return v.f;
}
__device__ __forceinline__ float bf2f(u16 x) { return bfu2f((unsigned)x); }
__device__ __forceinline__ u16 f2bf(float f) {
    union { float f; unsigned i; } v; v.f = f;
    unsigned r = v.i + 0x7FFFu + ((v.i >> 16) & 1u);
    return (u16)(r >> 16);
}
__device__ __forceinline__ u16 f2h_bits(float f) {
    union { f16t h; u16 u; } c; c.h = (f16t)f; return c.u;
}
__device__ __forceinline__ void unpack8(uint4 r, float* o) {
    o[0] = bfu2f(r.x & 0xffffu); o[1] = bfu2f(r.x >> 16);
    o[2] = bfu2f(r.y & 0xffffu); o[3] = bfu2f(r.y >> 16);
    o[4] = bfu2f(r.z & 0xffffu); o[5] = bfu2f(r.z >> 16);
    o[6] = bfu2f(r.w & 0xffffu); o[7] = bfu2f(r.w >> 16);
}
__device__ __forceinline__ void toh2x4(uint4 r, h2* o) {
    union { uint4 u; h2 h[4]; } c; c.u = r;
    o[0] = c.h[0]; o[1] = c.h[1]; o[2] = c.h[2]; o[3] = c.h[3];
}
__device__ __forceinline__ float tanh_f(float x) {
    x = fminf(15.f, fmaxf(-15.f, x));
    float e = __expf(2.f * x);
    return __fdividef(e - 1.f, e + 1.f);
}
__device__ __forceinline__ float sig_f(float x) {
    x = fminf(15.f, fmaxf(-15.f, x));
    return __fdividef(1.f, 1.f + __expf(-x));
}
// f32 polynomial tanh (clamped both ends) — used on the per-n final logit only
__device__ __forceinline__ float tanh_poly(float x) {
    x = fminf(3.25f, fmaxf(-3.25f, x));
    float z = x * x;
    float p = fmaf(fmaf(fmaf(-0.0018661f, z, 0.037231f), z, -0.249208f), z, 0.984238f);
    float r = x * p;
    return fminf(1.0f, fmaxf(-1.0f, r));
}
// packed-f16 tanh-dot step: s += dot2(vh, tanh_pk(qh + uh)). Input clamp to
// +-3.25 bounds |r|<=~1.03 (fit) — output clamp elided (error budget ~1e7x).
// pk_max/pk_min launder NaN like their f32 twins.
__device__ __forceinline__ float tanhdot_h2(h2 uh, h2 qh, h2 vh, float s) {
    const h2 kLo = { (f16t)-3.25f, (f16t)-3.25f };
    const h2 kHi = { (f16t)3.25f,  (f16t)3.25f };
    const h2 c3 = { (f16t)-0.0018661f, (f16t)-0.0018661f };
    const h2 c2 = { (f16t)0.037231f,   (f16t)0.037231f };
    const h2 c1 = { (f16t)-0.249208f,  (f16t)-0.249208f };
    const h2 c0 = { (f16t)0.984238f,   (f16t)0.984238f };
    h2 t = uh + qh;
    t = __builtin_elementwise_max(t, kLo);
    t = __builtin_elementwise_min(t, kHi);
    h2 z = t * t;
    h2 p = __builtin_elementwise_fma(c3, z, c2);
    p = __builtin_elementwise_fma(p, z, c1);
    p = __builtin_elementwise_fma(p, z, c0);
    h2 r = t * p;
#if defined(__has_builtin) && __has_builtin(__builtin_amdgcn_fdot2)
    return __builtin_amdgcn_fdot2(r, vh, s, false);
#else
    return s + (float)r.x * (float)vh.x + (float)r.y * (float)vh.y;
#endif
}
__device__ __forceinline__ f32x4 mfma16(bf16x8 a, bf16x8 b, f32x4 c) {
    return __builtin_amdgcn_mfma_f32_16x16x32_bf16(a, b, c, 0, 0, 0);
}

// ---------------------------------------------------------------------------
__global__ void sentinel_kernel(float* out) {
    int i = blockIdx.x * 256 + threadIdx.x;
    if (i < B_) out[BT_ + i] = 1.0e9f;   // signals "workspace too small"
}

// init: zero c, zero_h, ll; broadcast dec_input0 rows
__global__ void init_kernel(float* c, u16* zero_h, float* ll, u16* dec0_rows,
                            const u16* __restrict__ dec0) {
    int i = blockIdx.x * 256 + threadIdx.x;          // 262144 threads
    if (i < B_ * H_) { c[i] = 0.f; zero_h[i] = 0; }
    if (i < B_) ll[i] = 0.f;
    if (i < B_ * E_) dec0_rows[i] = dec0[i & (E_ - 1)];
}

// embed[b,n,e] = sum_p x[b,n,p] * emb_W[e,p]
__global__ void embed_kernel(const u16* __restrict__ x, const u16* __restrict__ emb_W,
                             u16* __restrict__ embed) {
    __shared__ float xs[P_];
    int bt = blockIdx.x, tid = threadIdx.x;
    if (tid < P_) xs[tid] = bf2f(x[(size_t)bt * P_ + tid]);
    __syncthreads();
    float s = 0.f;
#pragma unroll
    for (int p = 0; p < P_; ++p) s += xs[p] * bf2f(emb_W[tid * P_ + p]);
    embed[(size_t)bt * E_ + tid] = f2bf(s);
}

// mask[b,t,n] = #{s<t : y[b,s]==n}   (cumulative COUNT, y may repeat)
__global__ void mask_kernel(const int* __restrict__ y, unsigned char* __restrict__ mask) {
    int b = blockIdx.x, n = threadIdx.x;
    if (n >= N_) return;
    unsigned char cnt = 0;
    for (int t = 0; t < N_; ++t) {
        mask[((size_t)b * N_ + t) * N_ + n] = cnt;
        if (y[b * N_ + t] == n) cnt++;
    }
}

// ---------------------------------------------------------------------------
// Fused LSTM step v3 (verified R10): BK=64, 12 K-iterations.
__global__ __launch_bounds__(256) void fused3_step_kernel(
    const u16* __restrict__ h_base, int h_lda,
    const u16* __restrict__ x_base,
    const int* __restrict__ y,
    const u16* __restrict__ Whh, const u16* __restrict__ Wih,
    const u16* __restrict__ bih, const u16* __restrict__ bhh,
    float* __restrict__ cbuf,
    u16* __restrict__ hout,
    int mode, int t)
{
    __shared__ __align__(16) short As[64 * 72];
    __shared__ __align__(16) short Bs[64 * 72];
    const int tid = threadIdx.x;
    const int bn = blockIdx.x, bm = blockIdx.y;
    const int w = tid >> 6, l = tid & 63, rl = l & 15, q = l >> 4, q8 = q * 8;
    const int srow = tid >> 2, koff = (tid & 3) * 16;
    const int brw = bm * 64 + srow;

    const u16* hp = h_base + (size_t)brw * h_lda + koff;
    size_t xrow;
    if (mode == 0)      xrow = ((size_t)brw * N_ + t) * E_;
    else if (mode == 1) xrow = (size_t)brw * E_;
    else                xrow = ((size_t)brw * N_ + (size_t)y[brw * N_ + t - 1]) * E_;
    const u16* xp = x_base + xrow + koff;

    const int wrow = (srow >> 4) * 512 + bn * 16 + (srow & 15);
    const u16* whp = Whh + (size_t)wrow * H_ + koff;
    const u16* wip = Wih + (size_t)wrow * E_ + koff;

    float bsum[4];
#pragma unroll
    for (int g = 0; g < 4; ++g) {
        int col = g * 512 + bn * 16 + rl;
        bsum[g] = bf2f(bih[col]) + bf2f(bhh[col]);
    }

    f32x4 acc[4];
#pragma unroll
    for (int g = 0; g < 4; ++g) acc[g] = (f32x4){0.f, 0.f, 0.f, 0.f};

    uint4 aR0 = *(const uint4*)hp;
    uint4 aR1 = *(const uint4*)(hp + 8);
    uint4 bR0 = *(const uint4*)whp;
    uint4 bR1 = *(const uint4*)(whp + 8);

    short* asw = &As[srow * 72 + koff];
    short* bsw = &Bs[srow * 72 + koff];
    const short* arp = &As[(w * 16 + rl) * 72 + q8];

    for (int kt = 0; kt < 12; ++kt) {
        __syncthreads();
        *(uint4*)asw = aR0;  *(uint4*)(asw + 8) = aR1;
        *(uint4*)bsw = bR0;  *(uint4*)(bsw + 8) = bR1;
        __syncthreads();
        const int kn = kt + 1;
        if (kn < 12) {
            if (kn < 8) {
                aR0 = *(const uint4*)(hp + kn * 64);
                aR1 = *(const uint4*)(hp + kn * 64 + 8);
                bR0 = *(const uint4*)(whp + kn * 64);
                bR1 = *(const uint4*)(whp + kn * 64 + 8);
            } else {
                aR0 = *(const uint4*)(xp + (kn - 8) * 64);
                aR1 = *(const uint4*)(xp + (kn - 8) * 64 + 8);
                bR0 = *(const uint4*)(wip + (kn - 8) * 64);
                bR1 = *(const uint4*)(wip + (kn - 8) * 64 + 8);
            }
        }
        bf16x8 af0 = *(const bf16x8*)arp;
        bf16x8 af1 = *(const bf16x8*)(arp + 32);
#pragma unroll
        for (int g = 0; g < 4; ++g) {
            const short* brp = &Bs[(g * 16 + rl) * 72 + q8];
            bf16x8 b0 = *(const bf16x8*)brp;
            bf16x8 b1 = *(const bf16x8*)(brp + 32);
            acc[g] = mfma16(af0, b0, acc[g]);
            acc[g] = mfma16(af1, b1, acc[g]);
        }
    }

    const int hcol = bn * 16 + rl;
#pragma unroll
    for (int r = 0; r < 4; ++r) {
        int brow = bm * 64 + w * 16 + q * 4 + r;
        float gi = acc[0][r] + bsum[0];
        float gf = acc[1][r] + bsum[1];
        float gg = acc[2][r] + bsum[2];
        float go = acc[3][r] + bsum[3];
        size_t cidx = (size_t)brow * H_ + hcol;
        float cv = sig_f(gf) * cbuf[cidx] + sig_f(gi) * tanh_f(gg);
        cbuf[cidx] = cv;
        hout[(size_t)brow * (N_ * H_) + hcol] = f2bf(sig_f(go) * tanh_f(cv));
    }
}

// ---------------------------------------------------------------------------
// Head GEMM (R3-proven structure): C = A @ Bw^T + bias, 64x64 tile, BK=32.
// A,B bf16; C stored as **f16** (head kernels consume packed-f16).
__global__ __launch_bounds__(256) void gemm_bt_kernel(
    const u16* __restrict__ A, int lda,
    const u16* __restrict__ Bw,
    const u16* __restrict__ bias,
    u16* __restrict__ C, int ldc, int K)
{
    __shared__ __align__(16) short As[64 * 40];
    __shared__ __align__(16) short Bs[64 * 40];
    const int tid = threadIdx.x;
    const int bn = blockIdx.x, bm = blockIdx.y;
    const int srow = tid >> 2, koff = (tid & 3) * 8;
    const size_t aBase = (size_t)(bm * 64 + srow) * lda + koff;
    const size_t bBase = (size_t)(bn * 64 + srow) * K + koff;
    const int NKT = K >> 5;
    uint4 aReg = *(const uint4*)(A + aBase);
    uint4 bReg = *(const uint4*)(Bw + bBase);
    const int w = tid >> 6, l = tid & 63;
    const int wm = w & 1, wn = w >> 1;
    const int rl = l & 15, q8 = (l >> 4) * 8;
    f32x4 acc00 = {0.f,0.f,0.f,0.f}, acc01 = {0.f,0.f,0.f,0.f};
    f32x4 acc10 = {0.f,0.f,0.f,0.f}, acc11 = {0.f,0.f,0.f,0.f};
    short* asw = &As[srow * 40 + koff];
    short* bsw = &Bs[srow * 40 + koff];
    const short* ar0 = &As[(wm * 32 + rl) * 40 + q8];
    const short* ar1 = &As[(wm * 32 + 16 + rl) * 40 + q8];
    const short* br0 = &Bs[(wn * 32 + rl) * 40 + q8];
    const short* br1 = &Bs[(wn * 32 + 16 + rl) * 40 + q8];
    for (int kt = 0; kt < NKT; ++kt) {
        __syncthreads();
        *(uint4*)asw = aReg;
        *(uint4*)bsw = bReg;
        __syncthreads();
        if (kt + 1 < NKT) {
            aReg = *(const uint4*)(A + aBase + (kt + 1) * 32);
            bReg = *(const uint4*)(Bw + bBase + (kt + 1) * 32);
        }
        bf16x8 a0 = *(const bf16x8*)ar0;
        bf16x8 a1 = *(const bf16x8*)ar1;
        bf16x8 b0 = *(const bf16x8*)br0;
        bf16x8 b1 = *(const bf16x8*)br1;
        acc00 = mfma16(a0, b0, acc00);
        acc01 = mfma16(a0, b1, acc01);
        acc10 = mfma16(a1, b0, acc10);
        acc11 = mfma16(a1, b1, acc11);
    }
    const int col0 = bn * 64 + wn * 32 + rl;
    const int row0 = bm * 64 + wm * 32 + (l >> 4) * 4;
    const float bv0 = bias ? bf2f(bias[col0]) : 0.f;
    const float bv1 = bias ? bf2f(bias[col0 + 16]) : 0.f;
#pragma unroll
    for (int r = 0; r < 4; ++r) {
        C[(size_t)(row0 + r) * ldc + col0]           = f2h_bits(acc00[r] + bv0);
        C[(size_t)(row0 + r) * ldc + col0 + 16]      = f2h_bits(acc01[r] + bv1);
        C[(size_t)(row0 + 16 + r) * ldc + col0]      = f2h_bits(acc10[r] + bv0);
        C[(size_t)(row0 + 16 + r) * ldc + col0 + 16] = f2h_bits(acc11[r] + bv1);
    }
}

// ---------------------------------------------------------------------------
// Glimpse (R10 structure + masked-n skip) with packed-f16 tanh-dot inner loop.
// q1/u2g are f16; ref stays bf16; Vec converted bf16->f16 per lane.
__global__ __launch_bounds__(256) void glimpse_kernel(
    const u16* __restrict__ q1, const u16* __restrict__ u2g,
    const u16* __restrict__ ref, const u16* __restrict__ Vec,
    const unsigned char* __restrict__ mask, u16* __restrict__ query2)
{
    const int bt = blockIdx.x, b = bt / N_;
    const int tid = threadIdx.x, w = tid >> 6, l = tid & 63;
    __shared__ float u_s[N_], a_s[N_], red[8];
    __shared__ unsigned char msk[128];
    const int h0 = l * 8;
    h2 qh[4];
    toh2x4(*(const uint4*)(q1 + (size_t)bt * H_ + h0), qh);
    float vvf[8]; unpack8(*(const uint4*)(Vec + h0), vvf);
    h2 vh[4];
#pragma unroll
    for (int j = 0; j < 4; ++j) vh[j] = (h2){ (f16t)vvf[2*j], (f16t)vvf[2*j+1] };
    if (tid < 128) msk[tid] = (tid < N_) ? mask[(size_t)bt * N_ + tid] : 1;
    __syncthreads();
    const u16* ub = u2g + (size_t)b * N_ * H_;
    for (int n = w * 25; n < w * 25 + 25; ++n) {
        if (msk[n]) {                        // wave-uniform skip; u_s still init
            if (l == 0) u_s[n] = -3.0e38f;
            continue;
        }
        h2 uh[4];
        toh2x4(*(const uint4*)(ub + (size_t)n * H_ + h0), uh);
        float s = 0.f;
#pragma unroll
        for (int j = 0; j < 4; ++j) s = tanhdot_h2(uh[j], qh[j], vh[j], s);
#pragma unroll
        for (int off = 32; off > 0; off >>= 1) s += __shfl_xor(s, off, 64);
        if (l == 0) u_s[n] = s;
    }
    __syncthreads();
    float v = -3.0e38f;
    if (tid < N_ && msk[tid] == 0) v = u_s[tid];
    float m = v;
#pragma unroll
    for (int off = 32; off > 0; off >>= 1) m = fmaxf(m, __shfl_xor(m, off, 64));
    if (l == 0) red[w] = m;
    __syncthreads();
    float mx = fmaxf(fmaxf(red[0], red[1]), fmaxf(red[2], red[3]));
    float e = (tid < N_ && msk[tid] == 0) ? __expf(v - mx) : 0.f;
    float s2 = e;
#pragma unroll
    for (int off = 32; off > 0; off >>= 1) s2 += __shfl_xor(s2, off, 64);
    if (l == 0) red[4 + w] = s2;
    __syncthreads();
    float inv = __fdividef(1.f, red[4] + red[5] + red[6] + red[7]);
    if (tid < N_) a_s[tid] = e * inv;
    __syncthreads();
    const u16* refb = ref + (size_t)b * N_ * H_;
    float acc0 = 0.f, acc1 = 0.f;
    const int hh = tid * 2;
    for (int n = 0; n < N_; ++n) {
        float a = a_s[n];                    // block-uniform
        if (a == 0.f) continue;              // exact: zero contribution
        unsigned rr = *(const unsigned*)(refb + (size_t)n * H_ + hh);
        acc0 += a * bfu2f(rr & 0xffffu);
        acc1 += a * bfu2f(rr >> 16);
    }
    unsigned packed = ((unsigned)f2bf(acc1) << 16) | (unsigned)f2bf(acc0);
    *(unsigned*)(query2 + (size_t)bt * H_ + hh) = packed;
}

// Pointer head (R10 structure + masked-n skip), packed-f16 inner loop.
__global__ __launch_bounds__(256) void final_attn_kernel(
    const u16* __restrict__ q2, const u16* __restrict__ u2p,
    const u16* __restrict__ Vec2, const unsigned char* __restrict__ mask,
    const int* __restrict__ y, float* __restrict__ ll, float* __restrict__ ps)
{
    const int bt = blockIdx.x, b = bt / N_;
    const int tid = threadIdx.x, w = tid >> 6, l = tid & 63;
    __shared__ float u_s[N_], lp_s[N_], red[8];
    __shared__ unsigned char msk[128];
    const int h0 = l * 8;
    h2 qh[4];
    toh2x4(*(const uint4*)(q2 + (size_t)bt * H_ + h0), qh);
    float vvf[8]; unpack8(*(const uint4*)(Vec2 + h0), vvf);
    h2 vh[4];
#pragma unroll
    for (int j = 0; j < 4; ++j) vh[j] = (h2){ (f16t)vvf[2*j], (f16t)vvf[2*j+1] };
    if (tid < 128) msk[tid] = (tid < N_) ? mask[(size_t)bt * N_ + tid] : 1;
    __syncthreads();
    const u16* ub = u2p + (size_t)b * N_ * H_;
    for (int n = w * 25; n < w * 25 + 25; ++n) {
        if (msk[n]) {
            if (l == 0) u_s[n] = 0.f;        // unused but initialized
            continue;
        }
        h2 uh[4];
        toh2x4(*(const uint4*)(ub + (size_t)n * H_ + h0), uh);
        float s = 0.f;
#pragma unroll
        for (int j = 0; j < 4; ++j) s = tanhdot_h2(uh[j], qh[j], vh[j], s);
#pragma unroll
        for (int off = 32; off > 0; off >>= 1) s += __shfl_xor(s, off, 64);
        if (l == 0) u_s[n] = s;
    }
    __syncthreads();
    float lg = -3.0e38f;
    if (tid < N_) {
        unsigned char c = msk[tid];
        if (c) lg = -1e8f * (float)c;
        else   lg = 10.f * tanh_poly(u_s[tid]);
    }
    float m = lg;
#pragma unroll
    for (int off = 32; off > 0; off >>= 1) m = fmaxf(m, __shfl_xor(m, off, 64));
    if (l == 0) red[w] = m;
    __syncthreads();
    float mx = fmaxf(fmaxf(red[0], red[1]), fmaxf(red[2], red[3]));
    float e = (tid < N_) ? __expf(lg - mx) : 0.f;   // masked -> exactly 0
    float s2 = e;
#pragma unroll
    for (int off = 32; off > 0; off >>= 1) s2 += __shfl_xor(s2, off, 64);
    if (l == 0) red[4 + w] = s2;
    __syncthreads();
    float lse = mx + __logf(red[4] + red[5] + red[6] + red[7]);
    if (tid < N_) {
        float lp = lg - lse;
        ps[(size_t)bt * N_ + tid] = lp;
        lp_s[tid] = lp;
    }
    __syncthreads();
    if (tid == 0) atomicAdd(&ll[b], lp_s[y[bt]]);
}

// outputs (float32): pi = float(y); ll from f32 accumulator
__global__ void write_out_kernel(const int* __restrict__ y, const float* __restrict__ ll,
                                 float* __restrict__ out) {
    int i = blockIdx.x * 256 + threadIdx.x;   // 51200 threads
    if (i < BT_) out[i] = (float)y[i];
    if (i < B_)  out[BT_ + i] = ll[i];
}

// ---------------------------------------------------------------------------
extern "C" void kernel_launch(void* const* d_in, const int* in_sizes, int n_in,
                              void* d_out, int out_size, void* d_ws, size_t ws_size,
                              hipStream_t stream)
{
    const u16* x        = (const u16*)d_in[0];
    const int* y        = (const int*)d_in[1];
    const u16* emb_W    = (const u16*)d_in[2];
    const u16* enc_Wih  = (const u16*)d_in[3];
    const u16* enc_Whh  = (const u16*)d_in[4];
    const u16* enc_bih  = (const u16*)d_in[5];
    const u16* enc_bhh  = (const u16*)d_in[6];
    const u16* dec_Wih  = (const u16*)d_in[7];
    const u16* dec_Whh  = (const u16*)d_in[8];
    const u16* dec_bih  = (const u16*)d_in[9];
    const u16* dec_bhh  = (const u16*)d_in[10];
    const u16* Vec      = (const u16*)d_in[11];
    const u16* Vec2     = (const u16*)d_in[12];
    const u16* Wq_W     = (const u16*)d_in[13];
    const u16* Wq_b     = (const u16*)d_in[14];
    const u16* Wref_W   = (const u16*)d_in[15];
    const u16* Wref_b   = (const u16*)d_in[16];
    const u16* Wq2_W    = (const u16*)d_in[17];
    const u16* Wq2_b    = (const u16*)d_in[18];
    const u16* Wref2_W  = (const u16*)d_in[19];
    const u16* Wref2_b  = (const u16*)d_in[20];
    const u16* dec0     = (const u16*)d_in[21];

    char* p = (char*)d_ws;
    auto carve = [&](size_t bytes) -> char* {
        char* r = p; p += (bytes + 255) & ~(size_t)255; return r;
    };
    u16*   embed     = (u16*)  carve((size_t)BT_ * E_ * 2);      // 26.21 MB
    float* cbuf      = (float*)carve((size_t)B_ * H_ * 4);       //  1.05 MB
    u16*   zero_h    = (u16*)  carve((size_t)B_ * H_ * 2);       //  0.52 MB
    u16*   dec0_rows = (u16*)  carve((size_t)B_ * E_ * 2);       //  0.26 MB
    u16*   ref       = (u16*)  carve((size_t)BT_ * H_ * 2);      // 52.43 MB
    u16*   dec_hs    = (u16*)  carve((size_t)BT_ * H_ * 2);      // 52.43 MB (later: qry2)
    unsigned char* maskb = (unsigned char*)carve((size_t)BT_ * N_); // 5.12 MB
    float* llb       = (float*)carve((size_t)B_ * 4);
    const size_t need = (size_t)(p - (char*)d_ws);
    u16* Ybuf = embed;                                  // u2g / u2p chunk (f16)
    u16* Zbuf = embed + (size_t)BC_ * N_ * H_;          // q1 / q2 chunk (f16)

    if (need > ws_size) {
        sentinel_kernel<<<(B_ + 255) / 256, 256, 0, stream>>>((float*)d_out);
        return;
    }

    init_kernel<<<(B_ * H_) / 256, 256, 0, stream>>>(cbuf, zero_h, llb, dec0_rows, dec0);
    embed_kernel<<<BT_, 256, 0, stream>>>(x, emb_W, embed);
    mask_kernel<<<B_, 128, 0, stream>>>(y, maskb);

    dim3 sgrid(32, 8);   // hc tiles x batch tiles
    for (int t = 0; t < N_; ++t) {
        const u16* hb = (t == 0) ? zero_h : (ref + (size_t)(t - 1) * H_);
        int hlda = (t == 0) ? H_ : (N_ * H_);
        fused3_step_kernel<<<sgrid, 256, 0, stream>>>(hb, hlda, embed, y,
                                                      enc_Whh, enc_Wih, enc_bih, enc_bhh,
                                                      cbuf, ref + (size_t)t * H_, 0, t);
    }
    for (int t = 0; t < N_; ++t) {
        const u16* hb = (t == 0) ? (ref + (size_t)(N_ - 1) * H_) : (dec_hs + (size_t)(t - 1) * H_);
        const u16* xb = (t == 0) ? dec0_rows : embed;
        int mode = (t == 0) ? 1 : 2;
        fused3_step_kernel<<<sgrid, 256, 0, stream>>>(hb, N_ * H_, xb, y,
                                                      dec_Whh, dec_Wih, dec_bih, dec_bhh,
                                                      cbuf, dec_hs + (size_t)t * H_, mode, t);
    }

    // ---- batched attention, chunked over batch (embed now dead) ----
    float* out = (float*)d_out;
    const int MC = BC_ * N_;                     // 12800 rows per chunk
    dim3 cgrid(H_ / 64, MC / 64);                // (8, 200)
    for (int c = 0; c < NCHUNK_; ++c) {
        const size_t rowOff = (size_t)c * BC_ * N_ * H_;
        const size_t btOff  = (size_t)c * BC_ * N_;
        gemm_bt_kernel<<<cgrid, 256, 0, stream>>>(dec_hs + rowOff, H_, Wq_W,  Wq_b,  Zbuf, H_, H_);
        gemm_bt_kernel<<<cgrid, 256, 0, stream>>>(ref + rowOff,    H_, Wref_W, Wref_b, Ybuf, H_, H_);
        glimpse_kernel<<<MC, 256, 0, stream>>>(Zbuf, Ybuf, ref + rowOff, Vec,
                                               maskb + btOff * N_, dec_hs + rowOff);
        gemm_bt_kernel<<<cgrid, 256, 0, stream>>>(dec_hs + rowOff, H_, Wq2_W, Wq2_b, Zbuf, H_, H_);
        gemm_bt_kernel<<<cgrid, 256, 0, stream>>>(ref + rowOff,    H_, Wref2_W, Wref2_b, Ybuf, H_, H_);
        final_attn_kernel<<<MC, 256, 0, stream>>>(Zbuf, Ybuf, Vec2, maskb + btOff * N_,
                                                  y + btOff, llb + (size_t)c * BC_,
                                                  out + BT_ + B_ + btOff * N_);
    }
    write_out_kernel<<<BT_ / 256, 256, 0, stream>>>(y, llb, out);
}

// Round 12
// 3314.061 us; speedup vs baseline: 1.2187x; 1.2187x over previous
//
#include <hip/hip_runtime.h>
#include <hip/hip_bf16.h>
#include <stdint.h>

typedef unsigned short u16;
typedef __bf16 bf16t;
typedef _Float16 f16t;
typedef __attribute__((ext_vector_type(8))) bf16t bf16x8;
typedef __attribute__((ext_vector_type(4))) float f32x4;
typedef __attribute__((ext_vector_type(2))) _Float16 h2;

#define B_   512
#define N_   100
#define P_   20
#define E_   256
#define H_   512
#define G4H_ 2048
#define BT_  (B_ * N_)   // 51200
#define BC_  128         // phase-B batch chunk
#define NCHUNK_ (B_ / BC_)

__device__ __forceinline__ float bfu2f(unsigned u) {
    union { unsigned i; float f; } v; v.i = u << 16; return v.f;
}
__device__ __forceinline__ float bf2f(u16 x) { return bfu2f((unsigned)x); }
__device__ __forceinline__ u16 f2bf(float f) {
    union { float f; unsigned i; } v; v.f = f;
    unsigned r = v.i + 0x7FFFu + ((v.i >> 16) & 1u);
    return (u16)(r >> 16);
}
__device__ __forceinline__ u16 f2h_bits(float f) {
    union { f16t h; u16 u; } c; c.h = (f16t)f; return c.u;
}
__device__ __forceinline__ void unpack8(uint4 r, float* o) {
    o[0] = bfu2f(r.x & 0xffffu); o[1] = bfu2f(r.x >> 16);
    o[2] = bfu2f(r.y & 0xffffu); o[3] = bfu2f(r.y >> 16);
    o[4] = bfu2f(r.z & 0xffffu); o[5] = bfu2f(r.z >> 16);
    o[6] = bfu2f(r.w & 0xffffu); o[7] = bfu2f(r.w >> 16);
}
__device__ __forceinline__ void toh2x4(uint4 r, h2* o) {
    union { uint4 u; h2 h[4]; } c; c.u = r;
    o[0] = c.h[0]; o[1] = c.h[1]; o[2] = c.h[2]; o[3] = c.h[3];
}
__device__ __forceinline__ float tanh_f(float x) {
    x = fminf(15.f, fmaxf(-15.f, x));
    float e = __expf(2.f * x);
    return __fdividef(e - 1.f, e + 1.f);
}
__device__ __forceinline__ float sig_f(float x) {
    x = fminf(15.f, fmaxf(-15.f, x));
    return __fdividef(1.f, 1.f + __expf(-x));
}
// f32 polynomial tanh (clamped both ends) — used on the per-n final logit only
__device__ __forceinline__ float tanh_poly(float x) {
    x = fminf(3.25f, fmaxf(-3.25f, x));
    float z = x * x;
    float p = fmaf(fmaf(fmaf(-0.0018661f, z, 0.037231f), z, -0.249208f), z, 0.984238f);
    float r = x * p;
    return fminf(1.0f, fmaxf(-1.0f, r));
}
// packed-f16 tanh-dot step: s += dot2(vh, tanh_pk(qh + uh)). Input clamp to
// +-3.25 bounds |r|<=~1.03; pk max/min launder NaN.
__device__ __forceinline__ float tanhdot_h2(h2 uh, h2 qh, h2 vh, float s) {
    const h2 kLo = { (f16t)-3.25f, (f16t)-3.25f };
    const h2 kHi = { (f16t)3.25f,  (f16t)3.25f };
    const h2 c3 = { (f16t)-0.0018661f, (f16t)-0.0018661f };
    const h2 c2 = { (f16t)0.037231f,   (f16t)0.037231f };
    const h2 c1 = { (f16t)-0.249208f,  (f16t)-0.249208f };
    const h2 c0 = { (f16t)0.984238f,   (f16t)0.984238f };
    h2 t = uh + qh;
    t = __builtin_elementwise_max(t, kLo);
    t = __builtin_elementwise_min(t, kHi);
    h2 z = t * t;
    h2 p = __builtin_elementwise_fma(c3, z, c2);
    p = __builtin_elementwise_fma(p, z, c1);
    p = __builtin_elementwise_fma(p, z, c0);
    h2 r = t * p;
#if defined(__has_builtin) && __has_builtin(__builtin_amdgcn_fdot2)
    return __builtin_amdgcn_fdot2(r, vh, s, false);
#else
    return s + (float)r.x * (float)vh.x + (float)r.y * (float)vh.y;
#endif
}
__device__ __forceinline__ f32x4 mfma16(bf16x8 a, bf16x8 b, f32x4 c) {
    return __builtin_amdgcn_mfma_f32_16x16x32_bf16(a, b, c, 0, 0, 0);
}

// ---------------------------------------------------------------------------
__global__ void sentinel_kernel(float* out) {
    int i = blockIdx.x * 256 + threadIdx.x;
    if (i < B_) out[BT_ + i] = 1.0e9f;   // signals "workspace too small"
}

// init: zero c, zero_h, ll; broadcast dec_input0 rows
__global__ void init_kernel(float* c, u16* zero_h, float* ll, u16* dec0_rows,
                            const u16* __restrict__ dec0) {
    int i = blockIdx.x * 256 + threadIdx.x;          // 262144 threads
    if (i < B_ * H_) { c[i] = 0.f; zero_h[i] = 0; }
    if (i < B_) ll[i] = 0.f;
    if (i < B_ * E_) dec0_rows[i] = dec0[i & (E_ - 1)];
}

// embed[b,n,e] = sum_p x[b,n,p] * emb_W[e,p]
__global__ void embed_kernel(const u16* __restrict__ x, const u16* __restrict__ emb_W,
                             u16* __restrict__ embed) {
    __shared__ float xs[P_];
    int bt = blockIdx.x, tid = threadIdx.x;
    if (tid < P_) xs[tid] = bf2f(x[(size_t)bt * P_ + tid]);
    __syncthreads();
    float s = 0.f;
#pragma unroll
    for (int p = 0; p < P_; ++p) s += xs[p] * bf2f(emb_W[tid * P_ + p]);
    embed[(size_t)bt * E_ + tid] = f2bf(s);
}

// mask[b,t,n] = #{s<t : y[b,s]==n}   (cumulative COUNT, y may repeat)
__global__ void mask_kernel(const int* __restrict__ y, unsigned char* __restrict__ mask) {
    int b = blockIdx.x, n = threadIdx.x;
    if (n >= N_) return;
    unsigned char cnt = 0;
    for (int t = 0; t < N_; ++t) {
        mask[((size_t)b * N_ + t) * N_ + n] = cnt;
        if (y[b * N_ + t] == n) cnt++;
    }
}

// ---------------------------------------------------------------------------
// Fused LSTM step v3 (verified R10): BK=64, 12 K-iterations.
__global__ __launch_bounds__(256) void fused3_step_kernel(
    const u16* __restrict__ h_base, int h_lda,
    const u16* __restrict__ x_base,
    const int* __restrict__ y,
    const u16* __restrict__ Whh, const u16* __restrict__ Wih,
    const u16* __restrict__ bih, const u16* __restrict__ bhh,
    float* __restrict__ cbuf,
    u16* __restrict__ hout,
    int mode, int t)
{
    __shared__ __align__(16) short As[64 * 72];
    __shared__ __align__(16) short Bs[64 * 72];
    const int tid = threadIdx.x;
    const int bn = blockIdx.x, bm = blockIdx.y;
    const int w = tid >> 6, l = tid & 63, rl = l & 15, q = l >> 4, q8 = q * 8;
    const int srow = tid >> 2, koff = (tid & 3) * 16;
    const int brw = bm * 64 + srow;

    const u16* hp = h_base + (size_t)brw * h_lda + koff;
    size_t xrow;
    if (mode == 0)      xrow = ((size_t)brw * N_ + t) * E_;
    else if (mode == 1) xrow = (size_t)brw * E_;
    else                xrow = ((size_t)brw * N_ + (size_t)y[brw * N_ + t - 1]) * E_;
    const u16* xp = x_base + xrow + koff;

    const int wrow = (srow >> 4) * 512 + bn * 16 + (srow & 15);
    const u16* whp = Whh + (size_t)wrow * H_ + koff;
    const u16* wip = Wih + (size_t)wrow * E_ + koff;

    float bsum[4];
#pragma unroll
    for (int g = 0; g < 4; ++g) {
        int col = g * 512 + bn * 16 + rl;
        bsum[g] = bf2f(bih[col]) + bf2f(bhh[col]);
    }

    f32x4 acc[4];
#pragma unroll
    for (int g = 0; g < 4; ++g) acc[g] = (f32x4){0.f, 0.f, 0.f, 0.f};

    uint4 aR0 = *(const uint4*)hp;
    uint4 aR1 = *(const uint4*)(hp + 8);
    uint4 bR0 = *(const uint4*)whp;
    uint4 bR1 = *(const uint4*)(whp + 8);

    short* asw = &As[srow * 72 + koff];
    short* bsw = &Bs[srow * 72 + koff];
    const short* arp = &As[(w * 16 + rl) * 72 + q8];

    for (int kt = 0; kt < 12; ++kt) {
        __syncthreads();
        *(uint4*)asw = aR0;  *(uint4*)(asw + 8) = aR1;
        *(uint4*)bsw = bR0;  *(uint4*)(bsw + 8) = bR1;
        __syncthreads();
        const int kn = kt + 1;
        if (kn < 12) {
            if (kn < 8) {
                aR0 = *(const uint4*)(hp + kn * 64);
                aR1 = *(const uint4*)(hp + kn * 64 + 8);
                bR0 = *(const uint4*)(whp + kn * 64);
                bR1 = *(const uint4*)(whp + kn * 64 + 8);
            } else {
                aR0 = *(const uint4*)(xp + (kn - 8) * 64);
                aR1 = *(const uint4*)(xp + (kn - 8) * 64 + 8);
                bR0 = *(const uint4*)(wip + (kn - 8) * 64);
                bR1 = *(const uint4*)(wip + (kn - 8) * 64 + 8);
            }
        }
        bf16x8 af0 = *(const bf16x8*)arp;
        bf16x8 af1 = *(const bf16x8*)(arp + 32);
#pragma unroll
        for (int g = 0; g < 4; ++g) {
            const short* brp = &Bs[(g * 16 + rl) * 72 + q8];
            bf16x8 b0 = *(const bf16x8*)brp;
            bf16x8 b1 = *(const bf16x8*)(brp + 32);
            acc[g] = mfma16(af0, b0, acc[g]);
            acc[g] = mfma16(af1, b1, acc[g]);
        }
    }

    const int hcol = bn * 16 + rl;
#pragma unroll
    for (int r = 0; r < 4; ++r) {
        int brow = bm * 64 + w * 16 + q * 4 + r;
        float gi = acc[0][r] + bsum[0];
        float gf = acc[1][r] + bsum[1];
        float gg = acc[2][r] + bsum[2];
        float go = acc[3][r] + bsum[3];
        size_t cidx = (size_t)brow * H_ + hcol;
        float cv = sig_f(gf) * cbuf[cidx] + sig_f(gi) * tanh_f(gg);
        cbuf[cidx] = cv;
        hout[(size_t)brow * (N_ * H_) + hcol] = f2bf(sig_f(go) * tanh_f(cv));
    }
}

// ---------------------------------------------------------------------------
// Head GEMM (R3-proven structure): C = A @ Bw^T + bias, 64x64 tile, BK=32.
// A,B bf16; C stored as f16 (head kernels consume packed-f16).
__global__ __launch_bounds__(256) void gemm_bt_kernel(
    const u16* __restrict__ A, int lda,
    const u16* __restrict__ Bw,
    const u16* __restrict__ bias,
    u16* __restrict__ C, int ldc, int K)
{
    __shared__ __align__(16) short As[64 * 40];
    __shared__ __align__(16) short Bs[64 * 40];
    const int tid = threadIdx.x;
    const int bn = blockIdx.x, bm = blockIdx.y;
    const int srow = tid >> 2, koff = (tid & 3) * 8;
    const size_t aBase = (size_t)(bm * 64 + srow) * lda + koff;
    const size_t bBase = (size_t)(bn * 64 + srow) * K + koff;
    const int NKT = K >> 5;
    uint4 aReg = *(const uint4*)(A + aBase);
    uint4 bReg = *(const uint4*)(Bw + bBase);
    const int w = tid >> 6, l = tid & 63;
    const int wm = w & 1, wn = w >> 1;
    const int rl = l & 15, q8 = (l >> 4) * 8;
    f32x4 acc00 = {0.f,0.f,0.f,0.f}, acc01 = {0.f,0.f,0.f,0.f};
    f32x4 acc10 = {0.f,0.f,0.f,0.f}, acc11 = {0.f,0.f,0.f,0.f};
    short* asw = &As[srow * 40 + koff];
    short* bsw = &Bs[srow * 40 + koff];
    const short* ar0 = &As[(wm * 32 + rl) * 40 + q8];
    const short* ar1 = &As[(wm * 32 + 16 + rl) * 40 + q8];
    const short* br0 = &Bs[(wn * 32 + rl) * 40 + q8];
    const short* br1 = &Bs[(wn * 32 + 16 + rl) * 40 + q8];
    for (int kt = 0; kt < NKT; ++kt) {
        __syncthreads();
        *(uint4*)asw = aReg;
        *(uint4*)bsw = bReg;
        __syncthreads();
        if (kt + 1 < NKT) {
            aReg = *(const uint4*)(A + aBase + (kt + 1) * 32);
            bReg = *(const uint4*)(Bw + bBase + (kt + 1) * 32);
        }
        bf16x8 a0 = *(const bf16x8*)ar0;
        bf16x8 a1 = *(const bf16x8*)ar1;
        bf16x8 b0 = *(const bf16x8*)br0;
        bf16x8 b1 = *(const bf16x8*)br1;
        acc00 = mfma16(a0, b0, acc00);
        acc01 = mfma16(a0, b1, acc01);
        acc10 = mfma16(a1, b0, acc10);
        acc11 = mfma16(a1, b1, acc11);
    }
    const int col0 = bn * 64 + wn * 32 + rl;
    const int row0 = bm * 64 + wm * 32 + (l >> 4) * 4;
    const float bv0 = bias ? bf2f(bias[col0]) : 0.f;
    const float bv1 = bias ? bf2f(bias[col0 + 16]) : 0.f;
#pragma unroll
    for (int r = 0; r < 4; ++r) {
        C[(size_t)(row0 + r) * ldc + col0]           = f2h_bits(acc00[r] + bv0);
        C[(size_t)(row0 + r) * ldc + col0 + 16]      = f2h_bits(acc01[r] + bv1);
        C[(size_t)(row0 + 16 + r) * ldc + col0]      = f2h_bits(acc10[r] + bv0);
        C[(size_t)(row0 + 16 + r) * ldc + col0 + 16] = f2h_bits(acc11[r] + bv1);
    }
}

// ---------------------------------------------------------------------------
// Glimpse v5: ballot-compacted unmasked-n list -> branch-free, 2-way unrolled
// inner loop (loads pipelined); packed-f16 tanh-dot; list-driven PV.
__global__ __launch_bounds__(256) void glimpse_kernel(
    const u16* __restrict__ q1, const u16* __restrict__ u2g,
    const u16* __restrict__ ref, const u16* __restrict__ Vec,
    const unsigned char* __restrict__ mask, u16* __restrict__ query2)
{
    const int bt = blockIdx.x, b = bt / N_;
    const int tid = threadIdx.x, w = tid >> 6, l = tid & 63;
    __shared__ float u_s[N_], a_s[N_], red[8];
    __shared__ short list[N_];
    __shared__ int wcnt[2], cnt_s;
    const int h0 = l * 8;
    h2 qh[4];
    toh2x4(*(const uint4*)(q1 + (size_t)bt * H_ + h0), qh);
    float vvf[8]; unpack8(*(const uint4*)(Vec + h0), vvf);
    h2 vh[4];
#pragma unroll
    for (int j = 0; j < 4; ++j) vh[j] = (h2){ (f16t)vvf[2*j], (f16t)vvf[2*j+1] };
    // ---- compact unmasked n list (sorted) ----
    bool un = false;
    if (tid < N_) {
        un = (mask[(size_t)bt * N_ + tid] == 0);
        u_s[tid] = -3.0e38f;                 // init ALL entries (R6 scar)
    }
    unsigned long long bal = __ballot(un);
    if (l == 0 && w < 2) wcnt[w] = __popcll(bal);
    __syncthreads();
    const int base = (w == 1) ? wcnt[0] : 0;
    const int pos = __popcll(bal & ((1ULL << l) - 1ULL));
    if (un) list[base + pos] = (short)tid;
    if (tid == 0) cnt_s = wcnt[0] + wcnt[1];
    __syncthreads();
    const int cnt = cnt_s;
    const u16* ub = u2g + (size_t)b * N_ * H_;
    // wave w handles k == w (mod 4); unrolled pairs (k, k+4)
    for (int k = w; k < cnt; k += 8) {
        const int n0 = list[k];
        const int k1 = k + 4;
        const int n1 = (k1 < cnt) ? list[k1] : n0;
        h2 uh0[4], uh1[4];
        toh2x4(*(const uint4*)(ub + (size_t)n0 * H_ + h0), uh0);
        toh2x4(*(const uint4*)(ub + (size_t)n1 * H_ + h0), uh1);
        float s0 = 0.f, s1 = 0.f;
#pragma unroll
        for (int j = 0; j < 4; ++j) {
            s0 = tanhdot_h2(uh0[j], qh[j], vh[j], s0);
            s1 = tanhdot_h2(uh1[j], qh[j], vh[j], s1);
        }
#pragma unroll
        for (int off = 32; off > 0; off >>= 1) {
            s0 += __shfl_xor(s0, off, 64);
            s1 += __shfl_xor(s1, off, 64);
        }
        if (l == 0) {
            u_s[n0] = s0;
            if (k1 < cnt) u_s[n1] = s1;
        }
    }
    __syncthreads();
    float v = un ? u_s[tid] : -3.0e38f;
    float m = v;
#pragma unroll
    for (int off = 32; off > 0; off >>= 1) m = fmaxf(m, __shfl_xor(m, off, 64));
    if (l == 0) red[w] = m;
    __syncthreads();
    float mx = fmaxf(fmaxf(red[0], red[1]), fmaxf(red[2], red[3]));
    float e = un ? __expf(v - mx) : 0.f;
    float s2 = e;
#pragma unroll
    for (int off = 32; off > 0; off >>= 1) s2 += __shfl_xor(s2, off, 64);
    if (l == 0) red[4 + w] = s2;
    __syncthreads();
    float inv = __fdividef(1.f, red[4] + red[5] + red[6] + red[7]);
    if (tid < N_) a_s[tid] = e * inv;
    __syncthreads();
    // PV over compact list (branch-free)
    const u16* refb = ref + (size_t)b * N_ * H_;
    float acc0 = 0.f, acc1 = 0.f;
    const int hh = tid * 2;
    for (int k = 0; k < cnt; ++k) {
        const int n = list[k];
        float a = a_s[n];
        unsigned rr = *(const unsigned*)(refb + (size_t)n * H_ + hh);
        acc0 += a * bfu2f(rr & 0xffffu);
        acc1 += a * bfu2f(rr >> 16);
    }
    unsigned packed = ((unsigned)f2bf(acc1) << 16) | (unsigned)f2bf(acc0);
    *(unsigned*)(query2 + (size_t)bt * H_ + hh) = packed;
}

// Pointer head v5: same compaction + branch-free unrolled loop; masked logits
// use -1e8*cnt (|10*tanh|<=10 dropped — far under thresholds).
__global__ __launch_bounds__(256) void final_attn_kernel(
    const u16* __restrict__ q2, const u16* __restrict__ u2p,
    const u16* __restrict__ Vec2, const unsigned char* __restrict__ mask,
    const int* __restrict__ y, float* __restrict__ ll, float* __restrict__ ps)
{
    const int bt = blockIdx.x, b = bt / N_;
    const int tid = threadIdx.x, w = tid >> 6, l = tid & 63;
    __shared__ float u_s[N_], lp_s[N_], red[8];
    __shared__ short list[N_];
    __shared__ unsigned char msk[128];
    __shared__ int wcnt[2], cnt_s;
    const int h0 = l * 8;
    h2 qh[4];
    toh2x4(*(const uint4*)(q2 + (size_t)bt * H_ + h0), qh);
    float vvf[8]; unpack8(*(const uint4*)(Vec2 + h0), vvf);
    h2 vh[4];
#pragma unroll
    for (int j = 0; j < 4; ++j) vh[j] = (h2){ (f16t)vvf[2*j], (f16t)vvf[2*j+1] };
    bool un = false;
    if (tid < 128) msk[tid] = (tid < N_) ? mask[(size_t)bt * N_ + tid] : 1;
    if (tid < N_) {
        un = (msk[tid] == 0);                // own LDS write, own read: safe
        u_s[tid] = 0.f;                      // init ALL entries
    }
    unsigned long long bal = __ballot(un);
    if (l == 0 && w < 2) wcnt[w] = __popcll(bal);
    __syncthreads();
    const int base = (w == 1) ? wcnt[0] : 0;
    const int pos = __popcll(bal & ((1ULL << l) - 1ULL));
    if (un) list[base + pos] = (short)tid;
    if (tid == 0) cnt_s = wcnt[0] + wcnt[1];
    __syncthreads();
    const int cnt = cnt_s;
    const u16* ub = u2p + (size_t)b * N_ * H_;
    for (int k = w; k < cnt; k += 8) {
        const int n0 = list[k];
        const int k1 = k + 4;
        const int n1 = (k1 < cnt) ? list[k1] : n0;
        h2 uh0[4], uh1[4];
        toh2x4(*(const uint4*)(ub + (size_t)n0 * H_ + h0), uh0);
        toh2x4(*(const uint4*)(ub + (size_t)n1 * H_ + h0), uh1);
        float s0 = 0.f, s1 = 0.f;
#pragma unroll
        for (int j = 0; j < 4; ++j) {
            s0 = tanhdot_h2(uh0[j], qh[j], vh[j], s0);
            s1 = tanhdot_h2(uh1[j], qh[j], vh[j], s1);
        }
#pragma unroll
        for (int off = 32; off > 0; off >>= 1) {
            s0 += __shfl_xor(s0, off, 64);
            s1 += __shfl_xor(s1, off, 64);
        }
        if (l == 0) {
            u_s[n0] = s0;
            if (k1 < cnt) u_s[n1] = s1;
        }
    }
    __syncthreads();
    float lg = -3.0e38f;
    if (tid < N_) {
        unsigned char c = msk[tid];
        if (c) lg = -1e8f * (float)c;
        else   lg = 10.f * tanh_poly(u_s[tid]);
    }
    float m = lg;
#pragma unroll
    for (int off = 32; off > 0; off >>= 1) m = fmaxf(m, __shfl_xor(m, off, 64));
    if (l == 0) red[w] = m;
    __syncthreads();
    float mx = fmaxf(fmaxf(red[0], red[1]), fmaxf(red[2], red[3]));
    float e = (tid < N_) ? __expf(lg - mx) : 0.f;   // masked -> exactly 0
    float s2 = e;
#pragma unroll
    for (int off = 32; off > 0; off >>= 1) s2 += __shfl_xor(s2, off, 64);
    if (l == 0) red[4 + w] = s2;
    __syncthreads();
    float lse = mx + __logf(red[4] + red[5] + red[6] + red[7]);
    if (tid < N_) {
        float lp = lg - lse;
        ps[(size_t)bt * N_ + tid] = lp;
        lp_s[tid] = lp;
    }
    __syncthreads();
    if (tid == 0) atomicAdd(&ll[b], lp_s[y[bt]]);
}

// outputs (float32): pi = float(y); ll from f32 accumulator
__global__ void write_out_kernel(const int* __restrict__ y, const float* __restrict__ ll,
                                 float* __restrict__ out) {
    int i = blockIdx.x * 256 + threadIdx.x;   // 51200 threads
    if (i < BT_) out[i] = (float)y[i];
    if (i < B_)  out[BT_ + i] = ll[i];
}

// ---------------------------------------------------------------------------
extern "C" void kernel_launch(void* const* d_in, const int* in_sizes, int n_in,
                              void* d_out, int out_size, void* d_ws, size_t ws_size,
                              hipStream_t stream)
{
    const u16* x        = (const u16*)d_in[0];
    const int* y        = (const int*)d_in[1];
    const u16* emb_W    = (const u16*)d_in[2];
    const u16* enc_Wih  = (const u16*)d_in[3];
    const u16* enc_Whh  = (const u16*)d_in[4];
    const u16* enc_bih  = (const u16*)d_in[5];
    const u16* enc_bhh  = (const u16*)d_in[6];
    const u16* dec_Wih  = (const u16*)d_in[7];
    const u16* dec_Whh  = (const u16*)d_in[8];
    const u16* dec_bih  = (const u16*)d_in[9];
    const u16* dec_bhh  = (const u16*)d_in[10];
    const u16* Vec      = (const u16*)d_in[11];
    const u16* Vec2     = (const u16*)d_in[12];
    const u16* Wq_W     = (const u16*)d_in[13];
    const u16* Wq_b     = (const u16*)d_in[14];
    const u16* Wref_W   = (const u16*)d_in[15];
    const u16* Wref_b   = (const u16*)d_in[16];
    const u16* Wq2_W    = (const u16*)d_in[17];
    const u16* Wq2_b    = (const u16*)d_in[18];
    const u16* Wref2_W  = (const u16*)d_in[19];
    const u16* Wref2_b  = (const u16*)d_in[20];
    const u16* dec0     = (const u16*)d_in[21];

    char* p = (char*)d_ws;
    auto carve = [&](size_t bytes) -> char* {
        char* r = p; p += (bytes + 255) & ~(size_t)255; return r;
    };
    u16*   embed     = (u16*)  carve((size_t)BT_ * E_ * 2);      // 26.21 MB
    float* cbuf      = (float*)carve((size_t)B_ * H_ * 4);       //  1.05 MB
    u16*   zero_h    = (u16*)  carve((size_t)B_ * H_ * 2);       //  0.52 MB
    u16*   dec0_rows = (u16*)  carve((size_t)B_ * E_ * 2);       //  0.26 MB
    u16*   ref       = (u16*)  carve((size_t)BT_ * H_ * 2);      // 52.43 MB
    u16*   dec_hs    = (u16*)  carve((size_t)BT_ * H_ * 2);      // 52.43 MB (later: qry2)
    unsigned char* maskb = (unsigned char*)carve((size_t)BT_ * N_); // 5.12 MB
    float* llb       = (float*)carve((size_t)B_ * 4);
    const size_t need = (size_t)(p - (char*)d_ws);
    u16* Ybuf = embed;                                  // u2g / u2p chunk (f16)
    u16* Zbuf = embed + (size_t)BC_ * N_ * H_;          // q1 / q2 chunk (f16)

    if (need > ws_size) {
        sentinel_kernel<<<(B_ + 255) / 256, 256, 0, stream>>>((float*)d_out);
        return;
    }

    init_kernel<<<(B_ * H_) / 256, 256, 0, stream>>>(cbuf, zero_h, llb, dec0_rows, dec0);
    embed_kernel<<<BT_, 256, 0, stream>>>(x, emb_W, embed);
    mask_kernel<<<B_, 128, 0, stream>>>(y, maskb);

    dim3 sgrid(32, 8);   // hc tiles x batch tiles
    for (int t = 0; t < N_; ++t) {
        const u16* hb = (t == 0) ? zero_h : (ref + (size_t)(t - 1) * H_);
        int hlda = (t == 0) ? H_ : (N_ * H_);
        fused3_step_kernel<<<sgrid, 256, 0, stream>>>(hb, hlda, embed, y,
                                                      enc_Whh, enc_Wih, enc_bih, enc_bhh,
                                                      cbuf, ref + (size_t)t * H_, 0, t);
    }
    for (int t = 0; t < N_; ++t) {
        const u16* hb = (t == 0) ? (ref + (size_t)(N_ - 1) * H_) : (dec_hs + (size_t)(t - 1) * H_);
        const u16* xb = (t == 0) ? dec0_rows : embed;
        int mode = (t == 0) ? 1 : 2;
        fused3_step_kernel<<<sgrid, 256, 0, stream>>>(hb, N_ * H_, xb, y,
                                                      dec_Whh, dec_Wih, dec_bih, dec_bhh,
                                                      cbuf, dec_hs + (size_t)t * H_, mode, t);
    }

    // ---- batched attention, chunked over batch (embed now dead) ----
    float* out = (float*)d_out;
    const int MC = BC_ * N_;                     // 12800 rows per chunk
    dim3 cgrid(H_ / 64, MC / 64);                // (8, 200)
    for (int c = 0; c < NCHUNK_; ++c) {
        const size_t rowOff = (size_t)c * BC_ * N_ * H_;
        const size_t btOff  = (size_t)c * BC_ * N_;
        gemm_bt_kernel<<<cgrid, 256, 0, stream>>>(dec_hs + rowOff, H_, Wq_W,  Wq_b,  Zbuf, H_, H_);
        gemm_bt_kernel<<<cgrid, 256, 0, stream>>>(ref + rowOff,    H_, Wref_W, Wref_b, Ybuf, H_, H_);
        glimpse_kernel<<<MC, 256, 0, stream>>>(Zbuf, Ybuf, ref + rowOff, Vec,
                                               maskb + btOff * N_, dec_hs + rowOff);
        gemm_bt_kernel<<<cgrid, 256, 0, stream>>>(dec_hs + rowOff, H_, Wq2_W, Wq2_b, Zbuf, H_, H_);
        gemm_bt_kernel<<<cgrid, 256, 0, stream>>>(ref + rowOff,    H_, Wref2_W, Wref2_b, Ybuf, H_, H_);
        final_attn_kernel<<<MC, 256, 0, stream>>>(Zbuf, Ybuf, Vec2, maskb + btOff * N_,
                                                  y + btOff, llb + (size_t)c * BC_,
                                                  out + BT_ + B_ + btOff * N_);
    }
    write_out_kernel<<<BT_ / 256, 256, 0, stream>>>(y, llb, out);
}